// Round 9
// baseline (564.768 us; speedup 1.0000x reference)
//
#include <hip/hip_runtime.h>

// ---- problem constants ----
#define NC 256
#define NK 8
#define NS 30          // SAMPLE_K = N_TOP = 30
#define ICHN 16384     // L*D
#define CKN 2048       // C*K
#define MROWS 1024     // B*H
#define PLANE ((size_t)MROWS * CKN)   // one partial matrix, f32 elems
#define SCLQ (1.0f / 65536.0f)        // undo 256*256 split pre-scale

typedef _Float16 h4 __attribute__((ext_vector_type(4)));
typedef _Float16 h8 __attribute__((ext_vector_type(8)));
typedef float f4v __attribute__((ext_vector_type(4)));

// split f32 into hi/lo f16 pair, pre-scaled by 256 (exact pow2) so the lo part
// of the small weights (|w| <= 1/128) stays in f16 normal range. (validated r1-r8)
__device__ __forceinline__ void split4(const float4& x, h4& hi, h4& lo) {
  const float* xp = &x.x;
#pragma unroll
  for (int j = 0; j < 4; ++j) {
    float xs = xp[j] * 256.0f;
    _Float16 hh = (_Float16)xs;
    hi[j] = hh;
    lo[j] = (_Float16)(xs - (float)hh);
  }
}

// ============================================================================
// GEMM (K-split x KS): P[z*KS+ks][r][n] = sum_{i in ks-slice} act[r][i]*W[n][i]
// ROUND 9: 128x128 tile, 4 waves (2Mx2N, wave 64x64), BK=32 f32, 3-pass
// f16-split MFMA 16x16x32, double-buffered 64 KiB LDS -> TWO independent
// blocks/CU (separate barrier domains; m114 cross-block MFMA/VALU/LDS
// overlap).  Step anatomy, LDS row layout (8x16B chunks, hi 2q / lo 2q+1,
// chunk^(row&7) swizzle), staging shape (8 float4/thread/step) and the
// single-barrier double-buffered schedule are IDENTICAL to the validated R4
// structure -- only the tile geometry changes.  tn is the fastest grid dim so
// the 16 blocks sharing one act tile are dispatched adjacently (L2 locality).
// Scale (2^-16) and bias are applied in attn_tail during the partial reduce.
// ============================================================================
__global__ __launch_bounds__(256, 2) void gemm_split3(
    const float* __restrict__ qin, const float* __restrict__ kin,
    const float* __restrict__ Wq, const float* __restrict__ Wk,
    float* __restrict__ P, int KS, int KL, int nsteps) {
  __shared__ __align__(16) _Float16 ldsA[2][128][64];  // 32 KiB
  __shared__ __align__(16) _Float16 ldsB[2][128][64];  // 32 KiB

  const int tn = blockIdx.x & 15;  // 16 N-tiles (fastest: share act tile)
  const int tm = blockIdx.x >> 4;  // 8 M-tiles
  const int ksi = blockIdx.y;      // K-split slice
  const int z = blockIdx.z;        // 0=q, 1=k
  const float* act = z ? kin : qin;
  const float* W = z ? Wk : Wq;
  float* outp = P + (size_t)(z * KS + ksi) * PLANE;

  const int tid = threadIdx.x;
  // staging: thread owns row r = tid>>1 (of 128), f32 half gg = tid&1 (16 f32)
  const int r = tid >> 1;
  const int gg = tid & 1;
  const int R = tm * 128 + r;                  // global M row: b=R>>4, h=R&15
  const float* aP = act + (size_t)(R >> 4) * 262144 + (R & 15) * 64 +
                    (size_t)ksi * KL * 16 + gg * 16;
  const int n = tn * 128 + r;                  // global N row
  const float* bP = W + (size_t)n * 16384 + (size_t)ksi * KL + gg * 16;

  // LDS write offsets: groups q = 2gg, 2gg+1 -> hi chunk 2q, lo chunk 2q+1
  const int swW = r & 7;
  const int oh0 = r * 64 + (((4 * gg + 0) ^ swW) << 3);
  const int ol0 = r * 64 + (((4 * gg + 1) ^ swW) << 3);
  const int oh1 = r * 64 + (((4 * gg + 2) ^ swW) << 3);
  const int ol1 = r * 64 + (((4 * gg + 3) ^ swW) << 3);

  const int lane = tid & 63;
  const int wv = tid >> 6;     // wave 0..3
  const int wm = wv >> 1;      // 0..1  (64-row slice)
  const int wn = wv & 1;       // 0..1  (64-col slice)
  const int lr = lane & 15;
  const int lk = lane >> 4;    // k-group 0..3
  const int swR = lr & 7;
  const int aOffH = (wm * 64 + lr) * 64 + (((2 * lk) ^ swR) << 3);
  const int aOffL = (wm * 64 + lr) * 64 + (((2 * lk + 1) ^ swR) << 3);
  const int bOffH = (wn * 64 + lr) * 64 + (((2 * lk) ^ swR) << 3);
  const int bOffL = (wn * 64 + lr) * 64 + (((2 * lk + 1) ^ swR) << 3);

  f4v acc[4][4];
#pragma unroll
  for (int i = 0; i < 4; ++i)
#pragma unroll
    for (int j = 0; j < 4; ++j) acc[i][j] = (f4v){0.f, 0.f, 0.f, 0.f};

  float4 aS[4], bS[4];

  auto LOADT = [&](int s) {
    const size_t aoff = (size_t)(s >> 1) * 1024 + (s & 1) * 32;  // l=s>>1
    const size_t boff = (size_t)s * 32;
#pragma unroll
    for (int c = 0; c < 4; ++c) {
      aS[c] = *(const float4*)(aP + aoff + c * 4);
      bS[c] = *(const float4*)(bP + boff + c * 4);
    }
  };
  auto WRITES = [&](int bufi) {
    _Float16* bA = &ldsA[bufi][0][0];
    _Float16* bB = &ldsB[bufi][0][0];
    h4 h0, l0, h1, l1;
    split4(aS[0], h0, l0);
    split4(aS[1], h1, l1);
    *(h8*)(bA + oh0) = (h8){h0[0], h0[1], h0[2], h0[3], h1[0], h1[1], h1[2], h1[3]};
    *(h8*)(bA + ol0) = (h8){l0[0], l0[1], l0[2], l0[3], l1[0], l1[1], l1[2], l1[3]};
    split4(aS[2], h0, l0);
    split4(aS[3], h1, l1);
    *(h8*)(bA + oh1) = (h8){h0[0], h0[1], h0[2], h0[3], h1[0], h1[1], h1[2], h1[3]};
    *(h8*)(bA + ol1) = (h8){l0[0], l0[1], l0[2], l0[3], l1[0], l1[1], l1[2], l1[3]};
    split4(bS[0], h0, l0);
    split4(bS[1], h1, l1);
    *(h8*)(bB + oh0) = (h8){h0[0], h0[1], h0[2], h0[3], h1[0], h1[1], h1[2], h1[3]};
    *(h8*)(bB + ol0) = (h8){l0[0], l0[1], l0[2], l0[3], l1[0], l1[1], l1[2], l1[3]};
    split4(bS[2], h0, l0);
    split4(bS[3], h1, l1);
    *(h8*)(bB + oh1) = (h8){h0[0], h0[1], h0[2], h0[3], h1[0], h1[1], h1[2], h1[3]};
    *(h8*)(bB + ol1) = (h8){l0[0], l0[1], l0[2], l0[3], l1[0], l1[1], l1[2], l1[3]};
  };
  auto COMPUTE = [&](int bufi) {
    const _Float16* bA = &ldsA[bufi][0][0];
    const _Float16* bB = &ldsB[bufi][0][0];
    h8 Bh[4], Bl[4], Ah[4], Al[4];
#pragma unroll
    for (int fn = 0; fn < 4; ++fn) {
      Bh[fn] = *(const h8*)(bB + bOffH + fn * 1024);
      Bl[fn] = *(const h8*)(bB + bOffL + fn * 1024);
    }
#pragma unroll
    for (int fr = 0; fr < 4; ++fr) {
      Ah[fr] = *(const h8*)(bA + aOffH + fr * 1024);
      Al[fr] = *(const h8*)(bA + aOffL + fr * 1024);
    }
    __builtin_amdgcn_s_setprio(1);
#pragma unroll
    for (int fr = 0; fr < 4; ++fr)
#pragma unroll
      for (int fn = 0; fn < 4; ++fn) {
        f4v a = acc[fr][fn];
        a = __builtin_amdgcn_mfma_f32_16x16x32_f16(Ah[fr], Bh[fn], a, 0, 0, 0);
        a = __builtin_amdgcn_mfma_f32_16x16x32_f16(Ah[fr], Bl[fn], a, 0, 0, 0);
        a = __builtin_amdgcn_mfma_f32_16x16x32_f16(Al[fr], Bh[fn], a, 0, 0, 0);
        acc[fr][fn] = a;
      }
    __builtin_amdgcn_s_setprio(0);
  };

  LOADT(0);
  WRITES(0);
  __syncthreads();
  int cur = 0;
  for (int s = 0; s < nsteps; ++s) {
    if (s + 1 < nsteps) LOADT(s + 1);     // issue next-step loads early
    COMPUTE(cur);
    if (s + 1 < nsteps) WRITES(cur ^ 1);  // other buffer: safe concurrently
    __syncthreads();
    cur ^= 1;
  }

  // epilogue: raw partial accumulators (scale+bias applied in attn_tail)
#pragma unroll
  for (int fr = 0; fr < 4; ++fr)
#pragma unroll
    for (int fn = 0; fn < 4; ++fn) {
      int ocol = tn * 128 + wn * 64 + fn * 16 + lr;
#pragma unroll
      for (int j = 0; j < 4; ++j) {
        int orow = tm * 128 + wm * 64 + fr * 16 + lk * 4 + j;
        outp[(size_t)orow * CKN + ocol] = acc[fr][fn][j];
      }
    }
}

// ============================================================================
// Fused tail per (b,h): reduce K-split partials (+scale+bias) -> sampled-QK^T
// -> M -> top-30 (single wave) -> per-wave scores/softmax -> PV via MFMA ->
// cumsum(v as f16) with flagged rows skipped.  68 KB LDS -> 2 blocks/CU.
// (validated r8: qrow stash in phase 0, no global re-gather)
// ============================================================================
__global__ __launch_bounds__(256, 2) void attn_tail(
    const float* __restrict__ P, const float* __restrict__ bq,
    const float* __restrict__ bk, const float* __restrict__ values,
    const int* __restrict__ isamp, float* __restrict__ out, int KS) {
  __shared__ float kT[8][256];                     // 8 KB, [k][c]
  __shared__ float qrow[256][8];                   // 8 KB, [c][k]
  __shared__ __align__(16) _Float16 vT[64][256];   // 32 KB, [d][c] swizzled
  __shared__ __align__(16) _Float16 Pm[32][256];   // 16 KB, [u][c] swizzled
  __shared__ float MvC[256];
  __shared__ float csum4[4][64];
  __shared__ int idxl[NS];
  __shared__ int flagl[256];

  const int bh = blockIdx.x;
  const int b = bh >> 4, h = bh & 15;
  const int tid = threadIdx.x;
  const int w = tid >> 6, lane = tid & 63;
  const float* qpl = P;                        // q planes [0..KS)
  const float* kpl = P + (size_t)KS * PLANE;   // k planes [0..KS)
  float* obase = out + (size_t)bh * 16384;

  // ---- phase 0: kT (reduced+biased, transposed), qrow, vT f16, flags ----
  float qq[8];
  {
    float ks8[8];
    size_t rowo = (size_t)bh * CKN + tid * 8;
#pragma unroll
    for (int k = 0; k < 8; ++k) ks8[k] = 0.0f;
    for (int p = 0; p < KS; ++p) {
      float4 a0 = *(const float4*)(kpl + p * PLANE + rowo);
      float4 a1 = *(const float4*)(kpl + p * PLANE + rowo + 4);
      ks8[0] += a0.x; ks8[1] += a0.y; ks8[2] += a0.z; ks8[3] += a0.w;
      ks8[4] += a1.x; ks8[5] += a1.y; ks8[6] += a1.z; ks8[7] += a1.w;
    }
    float4 b0 = *(const float4*)(bk + tid * 8);
    float4 b1 = *(const float4*)(bk + tid * 8 + 4);
    kT[0][tid] = ks8[0] * SCLQ + b0.x; kT[1][tid] = ks8[1] * SCLQ + b0.y;
    kT[2][tid] = ks8[2] * SCLQ + b0.z; kT[3][tid] = ks8[3] * SCLQ + b0.w;
    kT[4][tid] = ks8[4] * SCLQ + b1.x; kT[5][tid] = ks8[5] * SCLQ + b1.y;
    kT[6][tid] = ks8[6] * SCLQ + b1.z; kT[7][tid] = ks8[7] * SCLQ + b1.w;
    // qq: this thread's own q row; stash to qrow for phase 4 broadcast
#pragma unroll
    for (int k = 0; k < 8; ++k) qq[k] = 0.0f;
    for (int p = 0; p < KS; ++p) {
      float4 a0 = *(const float4*)(qpl + p * PLANE + rowo);
      float4 a1 = *(const float4*)(qpl + p * PLANE + rowo + 4);
      qq[0] += a0.x; qq[1] += a0.y; qq[2] += a0.z; qq[3] += a0.w;
      qq[4] += a1.x; qq[5] += a1.y; qq[6] += a1.z; qq[7] += a1.w;
    }
    float4 c0 = *(const float4*)(bq + tid * 8);
    float4 c1 = *(const float4*)(bq + tid * 8 + 4);
    qq[0] = qq[0] * SCLQ + c0.x; qq[1] = qq[1] * SCLQ + c0.y;
    qq[2] = qq[2] * SCLQ + c0.z; qq[3] = qq[3] * SCLQ + c0.w;
    qq[4] = qq[4] * SCLQ + c1.x; qq[5] = qq[5] * SCLQ + c1.y;
    qq[6] = qq[6] * SCLQ + c1.z; qq[7] = qq[7] * SCLQ + c1.w;
    ((float4*)&qrow[tid][0])[0] = (float4){qq[0], qq[1], qq[2], qq[3]};
    ((float4*)&qrow[tid][0])[1] = (float4){qq[4], qq[5], qq[6], qq[7]};
    // vT: values[b,c,h,d] -> vT[d][c] f16 (chunk-swizzled)
    const float* vbase = values + (size_t)b * 262144 + h * 64;
#pragma unroll
    for (int rep = 0; rep < 16; ++rep) {
      int i = rep * 256 + tid;
      int c = i >> 4, dg = i & 15;
      float4 v = *(const float4*)(vbase + (size_t)c * 1024 + dg * 4);
      const float* vp = &v.x;
#pragma unroll
      for (int j = 0; j < 4; ++j) {
        int d = dg * 4 + j;
        vT[d][(((c >> 3) ^ (d & 7)) << 3) | (c & 7)] = (_Float16)vp[j];
      }
    }
    flagl[tid] = 0;
    if (tid < 64) {  // zero Pm pad rows 30,31
#pragma unroll
      for (int rr = 30; rr < 32; ++rr) {
        int ci = tid >> 1;
        *(h4*)&Pm[rr][((ci ^ (rr & 7)) << 3) | ((tid * 4) & 7)] =
            (h4){(_Float16)0, (_Float16)0, (_Float16)0, (_Float16)0};
      }
    }
  }
  __syncthreads();

  // ---- phase 1: M[c] = max_s QKs - sum_s QKs / 256 ----
  {
    float mx = -INFINITY, sm = 0.0f;
    const int* ip = isamp + tid * NS;
#pragma unroll 6
    for (int s = 0; s < NS; ++s) {
      int j = ip[s];
      float dot = 0.0f;
#pragma unroll
      for (int k = 0; k < NK; ++k) dot += qq[k] * kT[k][j];
      mx = fmaxf(mx, dot);
      sm += dot;
    }
    MvC[tid] = mx - sm * (1.0f / 256.0f);
  }
  __syncthreads();

  // ---- phase 2: top-30, single wave, shfl argmax (tie -> lower index) ----
  if (tid < 64) {
    float m0 = MvC[tid], m1 = MvC[tid + 64], m2 = MvC[tid + 128], m3 = MvC[tid + 192];
    for (int u = 0; u < NS; ++u) {
      float bv = m0; int bi = tid;
      if (m1 > bv) { bv = m1; bi = tid + 64; }
      if (m2 > bv) { bv = m2; bi = tid + 128; }
      if (m3 > bv) { bv = m3; bi = tid + 192; }
#pragma unroll
      for (int off = 32; off > 0; off >>= 1) {
        float ov = __shfl_xor(bv, off);
        int oi = __shfl_xor(bi, off);
        if (ov > bv || (ov == bv && oi < bi)) { bv = ov; bi = oi; }
      }
      if (tid == 0) { idxl[u] = bi; flagl[bi] = u + 1; }
      if (tid == (bi & 63)) {
        switch (bi >> 6) {
          case 0: m0 = -INFINITY; break;
          case 1: m1 = -INFINITY; break;
          case 2: m2 = -INFINITY; break;
          default: m3 = -INFINITY; break;
        }
      }
    }
  }
  __syncthreads();

  // ---- phase 4: per-wave u: scores -> softmax -> Pm (f16) ----
  for (int ui = w; ui < NS; ui += 4) {
    const int qi = idxl[ui];
    float qv[8];
#pragma unroll
    for (int k = 0; k < 8; ++k) qv[k] = qrow[qi][k];   // LDS broadcast
    float sj[4];
#pragma unroll
    for (int j = 0; j < 4; ++j) {
      int c = j * 64 + lane;
      float s = 0.0f;
#pragma unroll
      for (int k = 0; k < NK; ++k) s += qv[k] * kT[k][c];
      sj[j] = (c > qi) ? -INFINITY : s * 0.125f;       // SCALE=1/8, causal
    }
    float m = fmaxf(fmaxf(sj[0], sj[1]), fmaxf(sj[2], sj[3]));
#pragma unroll
    for (int off = 32; off > 0; off >>= 1) m = fmaxf(m, __shfl_xor(m, off));
    float pj[4], ts = 0.0f;
#pragma unroll
    for (int j = 0; j < 4; ++j) { pj[j] = __expf(sj[j] - m); ts += pj[j]; }
#pragma unroll
    for (int off = 32; off > 0; off >>= 1) ts += __shfl_xor(ts, off);
    float rinv = 1.0f / ts;
#pragma unroll
    for (int j = 0; j < 4; ++j) {
      int c = j * 64 + lane;
      Pm[ui][(((c >> 3) ^ (ui & 7)) << 3) | (c & 7)] = (_Float16)(pj[j] * rinv);
    }
  }
  __syncthreads();

  // ---- phase 5: upd = Pm(32x256) @ vT(256x64) via MFMA; wave w owns d-quarter
  {
    const int lr = lane & 15, lk = lane >> 4;
    f4v pacc[2];
    pacc[0] = (f4v){0.f, 0.f, 0.f, 0.f};
    pacc[1] = (f4v){0.f, 0.f, 0.f, 0.f};
#pragma unroll
    for (int kc = 0; kc < 8; ++kc) {
      int cidx = kc * 4 + lk;
      h8 Bv = *(const h8*)&vT[w * 16 + lr][((cidx ^ (lr & 7)) << 3)];
#pragma unroll
      for (int mf = 0; mf < 2; ++mf) {
        h8 Ap = *(const h8*)&Pm[mf * 16 + lr][((cidx ^ (lr & 7)) << 3)];
        pacc[mf] = __builtin_amdgcn_mfma_f32_16x16x32_f16(Ap, Bv, pacc[mf], 0, 0, 0);
      }
    }
#pragma unroll
    for (int mf = 0; mf < 2; ++mf)
#pragma unroll
      for (int j = 0; j < 4; ++j) {
        int u = mf * 16 + lk * 4 + j;
        if (u < NS) obase[(size_t)idxl[u] * 64 + w * 16 + lr] = pacc[mf][j];
      }
  }

  // ---- phase 6: cumsum(v) along l (f16 source), skip flagged rows ----
  {
    float cs = 0.0f;
#pragma unroll 8
    for (int i = 0; i < 64; ++i) {
      int c = w * 64 + i;
      cs += (float)vT[lane][(((c >> 3) ^ (lane & 7)) << 3) | (c & 7)];
    }
    csum4[w][lane] = cs;
    __syncthreads();
    float run = 0.0f;
    for (int j2 = 0; j2 < w; ++j2) run += csum4[j2][lane];
    for (int i = 0; i < 64; ++i) {
      int l = w * 64 + i;
      run += (float)vT[lane][(((l >> 3) ^ (lane & 7)) << 3) | (l & 7)];
      if (!flagl[l]) obase[(size_t)l * 64 + lane] = run;
    }
  }
}

extern "C" void kernel_launch(void* const* d_in, const int* in_sizes, int n_in,
                              void* d_out, int out_size, void* d_ws, size_t ws_size,
                              hipStream_t stream) {
  (void)in_sizes; (void)n_in; (void)out_size;
  const float* queries = (const float*)d_in[0];
  const float* keys = (const float*)d_in[1];
  const float* values = (const float*)d_in[2];
  const float* Wq_w = (const float*)d_in[3];
  const float* Wq_b = (const float*)d_in[4];
  const float* Wk_w = (const float*)d_in[5];
  const float* Wk_b = (const float*)d_in[6];
  // d_in[7], d_in[8] (Wv_w, Wv_b): dead in reference. d_in[10] attn_mask: unused.
  const int* index_sample = (const int*)d_in[9];
  float* out = (float*)d_out;

  float* P = (float*)d_ws;   // 2*KS partial planes [z][ks][1024][2048] f32

  // KS=4 needs 67.1 MB ws; fall back to KS=2 (33.5 MB, proven) if short.
  const int KS = (ws_size >= (size_t)8 * PLANE * 4) ? 4 : 2;
  const int KL = ICHN / KS;
  const int nsteps = KL / 32;

  dim3 gridG(128, KS, 2);   // x = tm*16 + tn (tn fastest: act-tile locality)
  gemm_split3<<<gridG, 256, 0, stream>>>(queries, keys, Wq_w, Wk_w, P, KS, KL, nsteps);
  attn_tail<<<dim3(MROWS), 256, 0, stream>>>(P, Wq_b, Wk_b, values, index_sample, out, KS);
}

// Round 10
// 452.482 us; speedup vs baseline: 1.2482x; 1.2482x over previous
//
#include <hip/hip_runtime.h>

// ---- problem constants ----
#define NC 256
#define NK 8
#define NS 30          // SAMPLE_K = N_TOP = 30
#define ICHN 16384     // L*D
#define CKN 2048       // C*K
#define MROWS 1024     // B*H
#define PLANE ((size_t)MROWS * CKN)   // one partial matrix, f32 elems
#define SCLQ (1.0f / 65536.0f)        // undo 256*256 split pre-scale

typedef _Float16 h4 __attribute__((ext_vector_type(4)));
typedef _Float16 h8 __attribute__((ext_vector_type(8)));
typedef float f4v __attribute__((ext_vector_type(4)));

// split f32 into hi/lo f16 pair, pre-scaled by 256 (exact pow2) so the lo part
// of the small weights (|w| <= 1/128) stays in f16 normal range. (validated r1-r9)
__device__ __forceinline__ void split4(const float4& x, h4& hi, h4& lo) {
  const float* xp = &x.x;
#pragma unroll
  for (int j = 0; j < 4; ++j) {
    float xs = xp[j] * 256.0f;
    _Float16 hh = (_Float16)xs;
    hi[j] = hh;
    lo[j] = (_Float16)(xs - (float)hh);
  }
}

// ============================================================================
// GEMM (K-split x KS): P[z*KS+ks][r][n] = sum_{i in ks-slice} act[r][i]*W[n][i]
// Tile M256 x N256, BK=32 f32 (64 f16), 512 threads = 8 waves (2Mx4N),
// wave-tile 128x64, 3-pass f16-split MFMA 16x16x32, double-buffered 128 KiB
// LDS, 1 block/CU.  == R4/R8 VERBATIM — VERIFIED OPTIMUM (380 us, 51%) ==
// Structure-probe ledger: R5 3-phase −15%, R6 32x32 −7%, R7 4-phase −26%,
// R9 half-tile 2-block −36%.  MFMA-busy time (194 us) == 3-pass MFMA floor
// (199 us): the matrix pipe does minimum required work; 51% overlap is this
// design family's measured ceiling under the in-loop f32->f16-split constraint.
// Scale (2^-16) and bias are applied in attn_tail during the partial reduce.
// ============================================================================
__global__ __launch_bounds__(512, 2) void gemm_split3(
    const float* __restrict__ qin, const float* __restrict__ kin,
    const float* __restrict__ Wq, const float* __restrict__ Wk,
    float* __restrict__ P, int KS, int KL, int nsteps) {
  __shared__ __align__(16) _Float16 ldsA[2][256][64];  // 64 KiB
  __shared__ __align__(16) _Float16 ldsB[2][256][64];  // 64 KiB

  const int tm = blockIdx.x & 3;   // 4 M-tiles
  const int tn = blockIdx.x >> 2;  // 8 N-tiles
  const int ksi = blockIdx.y;      // K-split slice
  const int z = blockIdx.z;        // 0=q, 1=k
  const float* act = z ? kin : qin;
  const float* W = z ? Wk : Wq;
  float* outp = P + (size_t)(z * KS + ksi) * PLANE;

  const int tid = threadIdx.x;
  // staging: thread owns row r = tid>>1 (of 256), f32 half gg = tid&1 (16 f32)
  const int r = tid >> 1;
  const int gg = tid & 1;
  const int R = tm * 256 + r;                  // global M row: b=R>>4, h=R&15
  const float* aP = act + (size_t)(R >> 4) * 262144 + (R & 15) * 64 +
                    (size_t)ksi * KL * 16 + gg * 16;
  const int n = tn * 256 + r;                  // global N row
  const float* bP = W + (size_t)n * 16384 + (size_t)ksi * KL + gg * 16;

  // LDS write offsets: groups q = 2gg, 2gg+1 -> hi chunk 2q, lo chunk 2q+1
  const int swW = r & 7;
  const int oh0 = r * 64 + (((4 * gg + 0) ^ swW) << 3);
  const int ol0 = r * 64 + (((4 * gg + 1) ^ swW) << 3);
  const int oh1 = r * 64 + (((4 * gg + 2) ^ swW) << 3);
  const int ol1 = r * 64 + (((4 * gg + 3) ^ swW) << 3);

  const int lane = tid & 63;
  const int wv = tid >> 6;     // wave 0..7
  const int wm = wv >> 2;      // 0..1  (128-row slice)
  const int wn = wv & 3;       // 0..3  (64-col slice)
  const int lr = lane & 15;
  const int lk = lane >> 4;    // k-group 0..3
  const int swR = lr & 7;
  const int aOffH = (wm * 128 + lr) * 64 + (((2 * lk) ^ swR) << 3);
  const int aOffL = (wm * 128 + lr) * 64 + (((2 * lk + 1) ^ swR) << 3);
  const int bOffH = (wn * 64 + lr) * 64 + (((2 * lk) ^ swR) << 3);
  const int bOffL = (wn * 64 + lr) * 64 + (((2 * lk + 1) ^ swR) << 3);

  f4v acc[8][4];
#pragma unroll
  for (int i = 0; i < 8; ++i)
#pragma unroll
    for (int j = 0; j < 4; ++j) acc[i][j] = (f4v){0.f, 0.f, 0.f, 0.f};

  float4 aS[4], bS[4];

  auto LOADT = [&](int s) {
    const size_t aoff = (size_t)(s >> 1) * 1024 + (s & 1) * 32;  // l=s>>1
    const size_t boff = (size_t)s * 32;
#pragma unroll
    for (int c = 0; c < 4; ++c) {
      aS[c] = *(const float4*)(aP + aoff + c * 4);
      bS[c] = *(const float4*)(bP + boff + c * 4);
    }
  };
  auto WRITES = [&](int bufi) {
    _Float16* bA = &ldsA[bufi][0][0];
    _Float16* bB = &ldsB[bufi][0][0];
    h4 h0, l0, h1, l1;
    split4(aS[0], h0, l0);
    split4(aS[1], h1, l1);
    *(h8*)(bA + oh0) = (h8){h0[0], h0[1], h0[2], h0[3], h1[0], h1[1], h1[2], h1[3]};
    *(h8*)(bA + ol0) = (h8){l0[0], l0[1], l0[2], l0[3], l1[0], l1[1], l1[2], l1[3]};
    split4(aS[2], h0, l0);
    split4(aS[3], h1, l1);
    *(h8*)(bA + oh1) = (h8){h0[0], h0[1], h0[2], h0[3], h1[0], h1[1], h1[2], h1[3]};
    *(h8*)(bA + ol1) = (h8){l0[0], l0[1], l0[2], l0[3], l1[0], l1[1], l1[2], l1[3]};
    split4(bS[0], h0, l0);
    split4(bS[1], h1, l1);
    *(h8*)(bB + oh0) = (h8){h0[0], h0[1], h0[2], h0[3], h1[0], h1[1], h1[2], h1[3]};
    *(h8*)(bB + ol0) = (h8){l0[0], l0[1], l0[2], l0[3], l1[0], l1[1], l1[2], l1[3]};
    split4(bS[2], h0, l0);
    split4(bS[3], h1, l1);
    *(h8*)(bB + oh1) = (h8){h0[0], h0[1], h0[2], h0[3], h1[0], h1[1], h1[2], h1[3]};
    *(h8*)(bB + ol1) = (h8){l0[0], l0[1], l0[2], l0[3], l1[0], l1[1], l1[2], l1[3]};
  };
  auto COMPUTE = [&](int bufi) {
    const _Float16* bA = &ldsA[bufi][0][0];
    const _Float16* bB = &ldsB[bufi][0][0];
    h8 Bh[4], Bl[4];
#pragma unroll
    for (int fn = 0; fn < 4; ++fn) {
      Bh[fn] = *(const h8*)(bB + bOffH + fn * 1024);
      Bl[fn] = *(const h8*)(bB + bOffL + fn * 1024);
    }
#pragma unroll
    for (int half = 0; half < 2; ++half) {
      h8 Ah[4], Al[4];
#pragma unroll
      for (int fr = 0; fr < 4; ++fr) {
        Ah[fr] = *(const h8*)(bA + aOffH + (half * 4 + fr) * 1024);
        Al[fr] = *(const h8*)(bA + aOffL + (half * 4 + fr) * 1024);
      }
      __builtin_amdgcn_s_setprio(1);
#pragma unroll
      for (int fr = 0; fr < 4; ++fr)
#pragma unroll
        for (int fn = 0; fn < 4; ++fn) {
          f4v a = acc[half * 4 + fr][fn];
          a = __builtin_amdgcn_mfma_f32_16x16x32_f16(Ah[fr], Bh[fn], a, 0, 0, 0);
          a = __builtin_amdgcn_mfma_f32_16x16x32_f16(Ah[fr], Bl[fn], a, 0, 0, 0);
          a = __builtin_amdgcn_mfma_f32_16x16x32_f16(Al[fr], Bh[fn], a, 0, 0, 0);
          acc[half * 4 + fr][fn] = a;
        }
      __builtin_amdgcn_s_setprio(0);
    }
  };

  LOADT(0);
  WRITES(0);
  __syncthreads();
  int cur = 0;
  for (int s = 0; s < nsteps; ++s) {
    if (s + 1 < nsteps) LOADT(s + 1);     // issue next-step loads early
    COMPUTE(cur);
    if (s + 1 < nsteps) WRITES(cur ^ 1);  // other buffer: safe concurrently
    __syncthreads();
    cur ^= 1;
  }

  // epilogue: raw partial accumulators (scale+bias applied in attn_tail)
#pragma unroll
  for (int fr = 0; fr < 8; ++fr)
#pragma unroll
    for (int fn = 0; fn < 4; ++fn) {
      int ocol = tn * 256 + wn * 64 + fn * 16 + lr;
#pragma unroll
      for (int j = 0; j < 4; ++j) {
        int orow = tm * 256 + wm * 128 + fr * 16 + lk * 4 + j;
        outp[(size_t)orow * CKN + ocol] = acc[fr][fn][j];
      }
    }
}

// ============================================================================
// Fused tail per (b,h): reduce K-split partials (+scale+bias) -> sampled-QK^T
// -> M -> top-30 (single wave) -> per-wave scores/softmax -> PV via MFMA ->
// cumsum(v as f16) with flagged rows skipped.  68 KB LDS -> 2 blocks/CU.
// (validated r8: qrow stash in phase 0, no global re-gather)
// ============================================================================
__global__ __launch_bounds__(256, 2) void attn_tail(
    const float* __restrict__ P, const float* __restrict__ bq,
    const float* __restrict__ bk, const float* __restrict__ values,
    const int* __restrict__ isamp, float* __restrict__ out, int KS) {
  __shared__ float kT[8][256];                     // 8 KB, [k][c]
  __shared__ float qrow[256][8];                   // 8 KB, [c][k]
  __shared__ __align__(16) _Float16 vT[64][256];   // 32 KB, [d][c] swizzled
  __shared__ __align__(16) _Float16 Pm[32][256];   // 16 KB, [u][c] swizzled
  __shared__ float MvC[256];
  __shared__ float csum4[4][64];
  __shared__ int idxl[NS];
  __shared__ int flagl[256];

  const int bh = blockIdx.x;
  const int b = bh >> 4, h = bh & 15;
  const int tid = threadIdx.x;
  const int w = tid >> 6, lane = tid & 63;
  const float* qpl = P;                        // q planes [0..KS)
  const float* kpl = P + (size_t)KS * PLANE;   // k planes [0..KS)
  float* obase = out + (size_t)bh * 16384;

  // ---- phase 0: kT (reduced+biased, transposed), qrow, vT f16, flags ----
  float qq[8];
  {
    float ks8[8];
    size_t rowo = (size_t)bh * CKN + tid * 8;
#pragma unroll
    for (int k = 0; k < 8; ++k) ks8[k] = 0.0f;
    for (int p = 0; p < KS; ++p) {
      float4 a0 = *(const float4*)(kpl + p * PLANE + rowo);
      float4 a1 = *(const float4*)(kpl + p * PLANE + rowo + 4);
      ks8[0] += a0.x; ks8[1] += a0.y; ks8[2] += a0.z; ks8[3] += a0.w;
      ks8[4] += a1.x; ks8[5] += a1.y; ks8[6] += a1.z; ks8[7] += a1.w;
    }
    float4 b0 = *(const float4*)(bk + tid * 8);
    float4 b1 = *(const float4*)(bk + tid * 8 + 4);
    kT[0][tid] = ks8[0] * SCLQ + b0.x; kT[1][tid] = ks8[1] * SCLQ + b0.y;
    kT[2][tid] = ks8[2] * SCLQ + b0.z; kT[3][tid] = ks8[3] * SCLQ + b0.w;
    kT[4][tid] = ks8[4] * SCLQ + b1.x; kT[5][tid] = ks8[5] * SCLQ + b1.y;
    kT[6][tid] = ks8[6] * SCLQ + b1.z; kT[7][tid] = ks8[7] * SCLQ + b1.w;
    // qq: this thread's own q row; stash to qrow for phase 4 broadcast
#pragma unroll
    for (int k = 0; k < 8; ++k) qq[k] = 0.0f;
    for (int p = 0; p < KS; ++p) {
      float4 a0 = *(const float4*)(qpl + p * PLANE + rowo);
      float4 a1 = *(const float4*)(qpl + p * PLANE + rowo + 4);
      qq[0] += a0.x; qq[1] += a0.y; qq[2] += a0.z; qq[3] += a0.w;
      qq[4] += a1.x; qq[5] += a1.y; qq[6] += a1.z; qq[7] += a1.w;
    }
    float4 c0 = *(const float4*)(bq + tid * 8);
    float4 c1 = *(const float4*)(bq + tid * 8 + 4);
    qq[0] = qq[0] * SCLQ + c0.x; qq[1] = qq[1] * SCLQ + c0.y;
    qq[2] = qq[2] * SCLQ + c0.z; qq[3] = qq[3] * SCLQ + c0.w;
    qq[4] = qq[4] * SCLQ + c1.x; qq[5] = qq[5] * SCLQ + c1.y;
    qq[6] = qq[6] * SCLQ + c1.z; qq[7] = qq[7] * SCLQ + c1.w;
    ((float4*)&qrow[tid][0])[0] = (float4){qq[0], qq[1], qq[2], qq[3]};
    ((float4*)&qrow[tid][0])[1] = (float4){qq[4], qq[5], qq[6], qq[7]};
    // vT: values[b,c,h,d] -> vT[d][c] f16 (chunk-swizzled)
    const float* vbase = values + (size_t)b * 262144 + h * 64;
#pragma unroll
    for (int rep = 0; rep < 16; ++rep) {
      int i = rep * 256 + tid;
      int c = i >> 4, dg = i & 15;
      float4 v = *(const float4*)(vbase + (size_t)c * 1024 + dg * 4);
      const float* vp = &v.x;
#pragma unroll
      for (int j = 0; j < 4; ++j) {
        int d = dg * 4 + j;
        vT[d][(((c >> 3) ^ (d & 7)) << 3) | (c & 7)] = (_Float16)vp[j];
      }
    }
    flagl[tid] = 0;
    if (tid < 64) {  // zero Pm pad rows 30,31
#pragma unroll
      for (int rr = 30; rr < 32; ++rr) {
        int ci = tid >> 1;
        *(h4*)&Pm[rr][((ci ^ (rr & 7)) << 3) | ((tid * 4) & 7)] =
            (h4){(_Float16)0, (_Float16)0, (_Float16)0, (_Float16)0};
      }
    }
  }
  __syncthreads();

  // ---- phase 1: M[c] = max_s QKs - sum_s QKs / 256 ----
  {
    float mx = -INFINITY, sm = 0.0f;
    const int* ip = isamp + tid * NS;
#pragma unroll 6
    for (int s = 0; s < NS; ++s) {
      int j = ip[s];
      float dot = 0.0f;
#pragma unroll
      for (int k = 0; k < NK; ++k) dot += qq[k] * kT[k][j];
      mx = fmaxf(mx, dot);
      sm += dot;
    }
    MvC[tid] = mx - sm * (1.0f / 256.0f);
  }
  __syncthreads();

  // ---- phase 2: top-30, single wave, shfl argmax (tie -> lower index) ----
  if (tid < 64) {
    float m0 = MvC[tid], m1 = MvC[tid + 64], m2 = MvC[tid + 128], m3 = MvC[tid + 192];
    for (int u = 0; u < NS; ++u) {
      float bv = m0; int bi = tid;
      if (m1 > bv) { bv = m1; bi = tid + 64; }
      if (m2 > bv) { bv = m2; bi = tid + 128; }
      if (m3 > bv) { bv = m3; bi = tid + 192; }
#pragma unroll
      for (int off = 32; off > 0; off >>= 1) {
        float ov = __shfl_xor(bv, off);
        int oi = __shfl_xor(bi, off);
        if (ov > bv || (ov == bv && oi < bi)) { bv = ov; bi = oi; }
      }
      if (tid == 0) { idxl[u] = bi; flagl[bi] = u + 1; }
      if (tid == (bi & 63)) {
        switch (bi >> 6) {
          case 0: m0 = -INFINITY; break;
          case 1: m1 = -INFINITY; break;
          case 2: m2 = -INFINITY; break;
          default: m3 = -INFINITY; break;
        }
      }
    }
  }
  __syncthreads();

  // ---- phase 4: per-wave u: scores -> softmax -> Pm (f16) ----
  for (int ui = w; ui < NS; ui += 4) {
    const int qi = idxl[ui];
    float qv[8];
#pragma unroll
    for (int k = 0; k < 8; ++k) qv[k] = qrow[qi][k];   // LDS broadcast
    float sj[4];
#pragma unroll
    for (int j = 0; j < 4; ++j) {
      int c = j * 64 + lane;
      float s = 0.0f;
#pragma unroll
      for (int k = 0; k < NK; ++k) s += qv[k] * kT[k][c];
      sj[j] = (c > qi) ? -INFINITY : s * 0.125f;       // SCALE=1/8, causal
    }
    float m = fmaxf(fmaxf(sj[0], sj[1]), fmaxf(sj[2], sj[3]));
#pragma unroll
    for (int off = 32; off > 0; off >>= 1) m = fmaxf(m, __shfl_xor(m, off));
    float pj[4], ts = 0.0f;
#pragma unroll
    for (int j = 0; j < 4; ++j) { pj[j] = __expf(sj[j] - m); ts += pj[j]; }
#pragma unroll
    for (int off = 32; off > 0; off >>= 1) ts += __shfl_xor(ts, off);
    float rinv = 1.0f / ts;
#pragma unroll
    for (int j = 0; j < 4; ++j) {
      int c = j * 64 + lane;
      Pm[ui][(((c >> 3) ^ (ui & 7)) << 3) | (c & 7)] = (_Float16)(pj[j] * rinv);
    }
  }
  __syncthreads();

  // ---- phase 5: upd = Pm(32x256) @ vT(256x64) via MFMA; wave w owns d-quarter
  {
    const int lr = lane & 15, lk = lane >> 4;
    f4v pacc[2];
    pacc[0] = (f4v){0.f, 0.f, 0.f, 0.f};
    pacc[1] = (f4v){0.f, 0.f, 0.f, 0.f};
#pragma unroll
    for (int kc = 0; kc < 8; ++kc) {
      int cidx = kc * 4 + lk;
      h8 Bv = *(const h8*)&vT[w * 16 + lr][((cidx ^ (lr & 7)) << 3)];
#pragma unroll
      for (int mf = 0; mf < 2; ++mf) {
        h8 Ap = *(const h8*)&Pm[mf * 16 + lr][((cidx ^ (lr & 7)) << 3)];
        pacc[mf] = __builtin_amdgcn_mfma_f32_16x16x32_f16(Ap, Bv, pacc[mf], 0, 0, 0);
      }
    }
#pragma unroll
    for (int mf = 0; mf < 2; ++mf)
#pragma unroll
      for (int j = 0; j < 4; ++j) {
        int u = mf * 16 + lk * 4 + j;
        if (u < NS) obase[(size_t)idxl[u] * 64 + w * 16 + lr] = pacc[mf][j];
      }
  }

  // ---- phase 6: cumsum(v) along l (f16 source), skip flagged rows ----
  {
    float cs = 0.0f;
#pragma unroll 8
    for (int i = 0; i < 64; ++i) {
      int c = w * 64 + i;
      cs += (float)vT[lane][(((c >> 3) ^ (lane & 7)) << 3) | (c & 7)];
    }
    csum4[w][lane] = cs;
    __syncthreads();
    float run = 0.0f;
    for (int j2 = 0; j2 < w; ++j2) run += csum4[j2][lane];
    for (int i = 0; i < 64; ++i) {
      int l = w * 64 + i;
      run += (float)vT[lane][(((l >> 3) ^ (lane & 7)) << 3) | (l & 7)];
      if (!flagl[l]) obase[(size_t)l * 64 + lane] = run;
    }
  }
}

extern "C" void kernel_launch(void* const* d_in, const int* in_sizes, int n_in,
                              void* d_out, int out_size, void* d_ws, size_t ws_size,
                              hipStream_t stream) {
  (void)in_sizes; (void)n_in; (void)out_size;
  const float* queries = (const float*)d_in[0];
  const float* keys = (const float*)d_in[1];
  const float* values = (const float*)d_in[2];
  const float* Wq_w = (const float*)d_in[3];
  const float* Wq_b = (const float*)d_in[4];
  const float* Wk_w = (const float*)d_in[5];
  const float* Wk_b = (const float*)d_in[6];
  // d_in[7], d_in[8] (Wv_w, Wv_b): dead in reference. d_in[10] attn_mask: unused.
  const int* index_sample = (const int*)d_in[9];
  float* out = (float*)d_out;

  float* P = (float*)d_ws;   // 2*KS partial planes [z][ks][1024][2048] f32

  // KS=4 needs 67.1 MB ws; fall back to KS=2 (33.5 MB, proven) if short.
  const int KS = (ws_size >= (size_t)8 * PLANE * 4) ? 4 : 2;
  const int KL = ICHN / KS;
  const int nsteps = KL / 32;

  dim3 gridG(32, KS, 2);
  gemm_split3<<<gridG, 512, 0, stream>>>(queries, keys, Wq_w, Wk_w, P, KS, KL, nsteps);
  attn_tail<<<dim3(MROWS), 256, 0, stream>>>(P, Wq_b, Wk_b, values, index_sample, out, KS);
}